// Round 12
// baseline (1634.646 us; speedup 1.0000x reference)
//
#include <hip/hip_runtime.h>
#include <hip/hip_cooperative_groups.h>
#include <math.h>

namespace cg = cooperative_groups;

#define CH 512
#define K 64
#define BB 8
#define NIMG 5
#define HW 1024
#define NP 5120   // NIMG*HW
#define BI 40     // BB*NIMG

typedef __attribute__((ext_vector_type(8))) _Float16 f16x8;
typedef __attribute__((ext_vector_type(4))) _Float16 f16x4;
typedef __attribute__((ext_vector_type(4))) float f32x4;
typedef __attribute__((ext_vector_type(8))) short s16x8;

#define AS1 __attribute__((address_space(1)))
#define AS3 __attribute__((address_space(3)))

// frag index for mu/B-operand: lane holds mu[k=l15+16j][c=cc*32+l4*8+e]
__device__ inline long mufrag_idx(int b, int c, int k) {
    int cc = c >> 5, l4 = (c >> 3) & 3, e = c & 7;
    int j = k >> 4, l15 = k & 15;
    int lane = l4 * 16 + l15;
    return ((long)b << 15) + (((cc * 4 + j) * 64 + lane) << 3) + e;
}

// ---------------- W fp32 -> fp16 (row-major copy) ---------------------------
__global__ __launch_bounds__(256) void wconv(const float* __restrict__ w,
                                             _Float16* __restrict__ o)
{
    int i = blockIdx.x * 256 + threadIdx.x;   // 262144
    o[i] = (_Float16)w[i];
}

// ---------------- transpose fp32 [z][512][P] -> fp16 [z][P][512] ------------
__global__ __launch_bounds__(256) void transpose_f16(
    const float* __restrict__ in, _Float16* __restrict__ out, int P)
{
    __shared__ float tile[64][65];
    int t = threadIdx.x;
    int p0 = blockIdx.x * 64, c0 = blockIdx.y * 64;
    long ibase = (long)blockIdx.z * CH * P;
    long obase = (long)blockIdx.z * P * CH;
    int pl = t & 63, chh = t >> 6;
    #pragma unroll
    for (int i = 0; i < 16; ++i)
        tile[chh + i * 4][pl] = in[ibase + (long)(c0 + chh + i * 4) * P + p0 + pl];
    __syncthreads();
    int cc = t & 31, pr = t >> 5;
    #pragma unroll
    for (int i = 0; i < 8; ++i) {
        int p = pr + i * 8;
        _Float16 lo = (_Float16)tile[cc * 2][p];
        _Float16 hi = (_Float16)tile[cc * 2 + 1][p];
        unsigned lob = (unsigned)*(unsigned short*)&lo;
        unsigned hib = (unsigned)*(unsigned short*)&hi;
        *(unsigned*)&out[obase + (long)(p0 + p) * CH + c0 + cc * 2] = lob | (hib << 16);
    }
}

// ---------------- broadcast mu -> mu_cur fp32 + muF frag-order fp16 ---------
__global__ __launch_bounds__(256) void bcast_mu2(const float* __restrict__ mu_in,
                                                 float* __restrict__ mu_cur,
                                                 _Float16* __restrict__ muF)
{
    int i = blockIdx.x * 256 + threadIdx.x;   // [b][c][k], 262144
    float v = mu_in[i & 32767];
    mu_cur[i] = v;
    int b = i >> 15, ck = i & 32767, c = ck >> 6, k = ck & 63;
    muF[mufrag_idx(b, c, k)] = (_Float16)v;
}

// ---------------- conv via single-buffer tiled MFMA + XCD swizzle -----------
__global__ __launch_bounds__(256) void conv_tile(
    const _Float16* __restrict__ Wh, const _Float16* __restrict__ inT,
    const float* __restrict__ bias, _Float16* __restrict__ y2h,
    _Float16* __restrict__ y16, _Float16* __restrict__ yT16, int mode)
{
    __shared__ _Float16 Wt[128 * 64];   // 16 KB
    __shared__ _Float16 Xt[128 * 64];   // 16 KB
    int t = threadIdx.x;
    int lane = t & 63, w = t >> 6;
    int l15 = lane & 15, l4 = lane >> 4;
    int wd = w & 1, wp = w >> 1;        // wave quadrant: 64d x 64p
    int sw = (blockIdx.x & 7) * 160 + (blockIdx.x >> 3);
    int px = sw & 7;            // p-tile
    int dy = (sw >> 3) & 3;     // d-tile
    int bi = sw >> 5;           // image
    int d0 = dy * 128;
    int pl0 = px * 128;
    long prow0 = (long)bi * HW + pl0;
    int ci_row = lane >> 3;
    int colb_phys = (lane & 7) * 16;

    f32x4 acc[4][4];
    #pragma unroll
    for (int ai = 0; ai < 4; ++ai)
        #pragma unroll
        for (int bj = 0; bj < 4; ++bj) acc[ai][bj] = (f32x4){0.f, 0.f, 0.f, 0.f};

    for (int c0 = 0; c0 < CH; c0 += 64) {
        __syncthreads();
        #pragma unroll
        for (int i = 0; i < 4; ++i) {
            int row = w * 32 + i * 8 + ci_row;
            int cb = colb_phys ^ ((row & 7) << 4);
            const _Float16* srcW = Wh + (long)(d0 + row) * CH + c0 + (cb >> 1);
            const _Float16* srcX = inT + (prow0 + row) * (long)CH + c0 + (cb >> 1);
            __builtin_amdgcn_global_load_lds((const AS1 void*)srcW,
                (AS3 void*)&Wt[(w * 32 + i * 8) * 64], 16, 0, 0);
            __builtin_amdgcn_global_load_lds((const AS1 void*)srcX,
                (AS3 void*)&Xt[(w * 32 + i * 8) * 64], 16, 0, 0);
        }
        __syncthreads();
        #pragma unroll
        for (int kk = 0; kk < 2; ++kk) {
            f16x8 af[4], bf[4];
            #pragma unroll
            for (int ai = 0; ai < 4; ++ai) {
                int row = wd * 64 + ai * 16 + l15;
                int cb = (kk * 64 + l4 * 16) ^ ((row & 7) << 4);
                af[ai] = *(const f16x8*)((const char*)Wt + row * 128 + cb);
            }
            #pragma unroll
            for (int bj = 0; bj < 4; ++bj) {
                int row = wp * 64 + bj * 16 + l15;
                int cb = (kk * 64 + l4 * 16) ^ ((row & 7) << 4);
                bf[bj] = *(const f16x8*)((const char*)Xt + row * 128 + cb);
            }
            #pragma unroll
            for (int ai = 0; ai < 4; ++ai)
                #pragma unroll
                for (int bj = 0; bj < 4; ++bj)
                    acc[ai][bj] = __builtin_amdgcn_mfma_f32_16x16x32_f16(
                        af[ai], bf[bj], acc[ai][bj], 0, 0, 0);
        }
    }

    int b = bi / NIMG, n = bi % NIMG;
    if (mode == 0) {
        #pragma unroll
        for (int ai = 0; ai < 4; ++ai) {
            int dd = d0 + wd * 64 + ai * 16 + l4 * 4;
            float b0 = bias[dd], b1 = bias[dd + 1], b2 = bias[dd + 2], b3 = bias[dd + 3];
            #pragma unroll
            for (int bj = 0; bj < 4; ++bj) {
                int pb = n * HW + pl0 + wp * 64 + bj * 16 + l15;
                f16x4 pk = { (_Float16)(acc[ai][bj][0] + b0), (_Float16)(acc[ai][bj][1] + b1),
                             (_Float16)(acc[ai][bj][2] + b2), (_Float16)(acc[ai][bj][3] + b3) };
                *(f16x4*)&yT16[((long)b * NP + pb) * CH + dd] = pk;
                long yb = ((long)b * CH + dd) * NP + pb;
                y16[yb] = pk[0];
                y16[yb + NP] = pk[1];
                y16[yb + 2 * NP] = pk[2];
                y16[yb + 3 * NP] = pk[3];
            }
        }
    } else {
        long obase = (long)bi * CH * HW;
        #pragma unroll
        for (int ai = 0; ai < 4; ++ai) {
            int dd = d0 + wd * 64 + ai * 16 + l4 * 4;
            #pragma unroll
            for (int bj = 0; bj < 4; ++bj) {
                int p = pl0 + wp * 64 + bj * 16 + l15;
                long o = obase + (long)dd * HW + p;
                y2h[o] = (_Float16)acc[ai][bj][0];
                y2h[o + HW] = (_Float16)acc[ai][bj][1];
                y2h[o + 2 * HW] = (_Float16)acc[ai][bj][2];
                y2h[o + 3 * HW] = (_Float16)acc[ai][bj][3];
            }
        }
    }
}

// ======= standalone EM kernels (round-10 proven; used as fallback) ==========
__global__ __launch_bounds__(256) void stage_z_mfma(
    const _Float16* __restrict__ yT, const _Float16* __restrict__ muF,
    _Float16* __restrict__ zT, _Float16* __restrict__ z16,
    float* __restrict__ zsum, int writeZ)
{
    __shared__ float zred[256];
    int t = threadIdx.x;
    int w = t >> 6, lane = t & 63, l15 = lane & 15, l4 = lane >> 4;
    int p0 = blockIdx.x * 64 + w * 16;
    int b = blockIdx.y;
    const _Float16* mf = muF + ((long)b << 15);
    const _Float16* a0p = yT + ((long)b * NP + p0 + l15) * CH + l4 * 8;
    f32x4 acc[4];
    #pragma unroll
    for (int j = 0; j < 4; ++j) acc[j] = (f32x4){0.f, 0.f, 0.f, 0.f};
    #pragma unroll
    for (int cc = 0; cc < 16; ++cc) {
        f16x8 a0 = *(const f16x8*)(a0p + cc * 32);
        #pragma unroll
        for (int j = 0; j < 4; ++j) {
            f16x8 bj = *(const f16x8*)&muF[((long)b << 15) + ((((cc * 4 + j) * 64) + lane) << 3)];
            acc[j] = __builtin_amdgcn_mfma_f32_16x16x32_f16(a0, bj, acc[j], 0, 0, 0);
        }
    }
    float zv[4][4];
    #pragma unroll
    for (int i = 0; i < 4; ++i) {
        float m = fmaxf(fmaxf(acc[0][i], acc[1][i]), fmaxf(acc[2][i], acc[3][i]));
        #pragma unroll
        for (int off = 1; off < 16; off <<= 1) m = fmaxf(m, __shfl_xor(m, off, 64));
        float e0 = __expf(acc[0][i] - m);
        float e1 = __expf(acc[1][i] - m);
        float e2 = __expf(acc[2][i] - m);
        float e3 = __expf(acc[3][i] - m);
        float s = e0 + e1 + e2 + e3;
        #pragma unroll
        for (int off = 1; off < 16; off <<= 1) s += __shfl_xor(s, off, 64);
        float inv = 1.f / s;
        zv[0][i] = e0 * inv; zv[1][i] = e1 * inv;
        zv[2][i] = e2 * inv; zv[3][i] = e3 * inv;
    }
    int prow = p0 + l4 * 4;
    long ztbase = (long)b * K * NP;
    #pragma unroll
    for (int j = 0; j < 4; ++j) {
        f16x4 pk = { (_Float16)zv[j][0], (_Float16)zv[j][1],
                     (_Float16)zv[j][2], (_Float16)zv[j][3] };
        *(f16x4*)&zT[ztbase + (long)(l15 + 16 * j) * NP + prow] = pk;
    }
    if (writeZ) {
        long zbase = (long)b * NP * K;
        #pragma unroll
        for (int j = 0; j < 4; ++j)
            #pragma unroll
            for (int i = 0; i < 4; ++i)
                z16[zbase + (long)(prow + i) * K + l15 + 16 * j] = (_Float16)zv[j][i];
    }
    float part[4];
    #pragma unroll
    for (int j = 0; j < 4; ++j) {
        part[j] = zv[j][0] + zv[j][1] + zv[j][2] + zv[j][3];
        part[j] += __shfl_xor(part[j], 16, 64);
        part[j] += __shfl_xor(part[j], 32, 64);
    }
    if (l4 == 0) {
        #pragma unroll
        for (int j = 0; j < 4; ++j) zred[w * 64 + l15 + 16 * j] = part[j];
    }
    __syncthreads();
    if (t < 64)
        atomicAdd(&zsum[b * 64 + t], zred[t] + zred[64 + t] + zred[128 + t] + zred[192 + t]);
}

__global__ __launch_bounds__(256) void stage_mu_mfma(
    const _Float16* __restrict__ y16, const _Float16* __restrict__ zT,
    float* __restrict__ macc)
{
    int t = threadIdx.x;
    int w = t >> 6, lane = t & 63, l15 = lane & 15, l4 = lane >> 4;
    int pc = blockIdx.x, ct = blockIdx.y, b = blockIdx.z;
    int c0 = ct * 128 + w * 32;
    int pbase = pc * 320;
    const _Float16* zrow = zT + (long)b * K * NP + (long)l15 * NP + l4 * 8;
    const _Float16* a0p = y16 + ((long)b * CH + c0 + l15) * NP + l4 * 8;
    const _Float16* a1p = y16 + ((long)b * CH + c0 + 16 + l15) * NP + l4 * 8;
    f32x4 acc[2][4];
    #pragma unroll
    for (int ci = 0; ci < 2; ++ci)
        #pragma unroll
        for (int j = 0; j < 4; ++j) acc[ci][j] = (f32x4){0.f, 0.f, 0.f, 0.f};
    for (int p0 = pbase; p0 < pbase + 320; p0 += 32) {
        f16x8 a0 = *(const f16x8*)(a0p + p0);
        f16x8 a1 = *(const f16x8*)(a1p + p0);
        #pragma unroll
        for (int j = 0; j < 4; ++j) {
            f16x8 bj = *(const f16x8*)(zrow + (long)(16 * j) * NP + p0);
            acc[0][j] = __builtin_amdgcn_mfma_f32_16x16x32_f16(a0, bj, acc[0][j], 0, 0, 0);
            acc[1][j] = __builtin_amdgcn_mfma_f32_16x16x32_f16(a1, bj, acc[1][j], 0, 0, 0);
        }
    }
    float* mp = macc + ((long)pc * BB + b) * K * CH;
    #pragma unroll
    for (int ci = 0; ci < 2; ++ci)
        #pragma unroll
        for (int j = 0; j < 4; ++j)
            *(f32x4*)&mp[(long)(l15 + 16 * j) * CH + c0 + ci * 16 + l4 * 4] = acc[ci][j];
}

__global__ __launch_bounds__(256) void mu_norm2(
    const float* __restrict__ macc, const float* __restrict__ zsum,
    float* __restrict__ mu_cur, _Float16* __restrict__ mu16,
    _Float16* __restrict__ muF)
{
    int gw = blockIdx.x * 4 + (threadIdx.x >> 6);   // 512 = 8b x 64k
    int lane = threadIdx.x & 63;
    int b = gw >> 6, k = gw & 63;
    float v[8];
    float s = 0.f;
    #pragma unroll
    for (int ci = 0; ci < 8; ++ci) {
        int c = ci * 64 + lane;
        float a = 0.f;
        #pragma unroll
        for (int pcc = 0; pcc < 16; ++pcc)
            a += macc[(((long)pcc * BB + b) * K + k) * CH + c];
        v[ci] = a; s += a * a;
    }
    #pragma unroll
    for (int off = 1; off < 64; off <<= 1) s += __shfl_xor(s, off, 64);
    float d = 1e-6f + zsum[b * 64 + k];
    float scale = 1.f / (1e-6f * d + sqrtf(s));
    long mb = (long)b << 15;
    #pragma unroll
    for (int ci = 0; ci < 8; ++ci) {
        int c = ci * 64 + lane;
        float m = v[ci] * scale;
        mu_cur[mb + (long)c * K + k] = m;
        mu16[mb + (long)c * K + k] = (_Float16)m;
        muF[mufrag_idx(b, c, k)] = (_Float16)m;
    }
}

__global__ __launch_bounds__(256) void rec_mfma(
    const _Float16* __restrict__ z16, const _Float16* __restrict__ mu16,
    _Float16* __restrict__ recT)
{
    __shared__ _Float16 rt[64 * 80];
    int t = threadIdx.x;
    int w = t >> 6, lane = t & 63, l15 = lane & 15, l4 = lane >> 4;
    int p0 = blockIdx.x * 64, ct = blockIdx.y, b = blockIdx.z;
    const _Float16* zb = z16 + (long)b * NP * K;
    const _Float16* mb = mu16 + ((long)b << 15) + (long)(ct * 64 + w * 16 + l15) * K + l4 * 8;
    f32x4 acc[4];
    #pragma unroll
    for (int pj = 0; pj < 4; ++pj) acc[pj] = (f32x4){0.f, 0.f, 0.f, 0.f};
    #pragma unroll
    for (int kc = 0; kc < 64; kc += 32) {
        f16x8 bfr = *(const f16x8*)(mb + kc);
        #pragma unroll
        for (int pj = 0; pj < 4; ++pj) {
            f16x8 a = *(const f16x8*)(zb + (long)(p0 + pj * 16 + l15) * K + kc + l4 * 8);
            acc[pj] = __builtin_amdgcn_mfma_f32_16x16x32_f16(a, bfr, acc[pj], 0, 0, 0);
        }
    }
    #pragma unroll
    for (int pj = 0; pj < 4; ++pj)
        #pragma unroll
        for (int i = 0; i < 4; ++i)
            rt[(pj * 16 + l4 * 4 + i) * 80 + w * 16 + l15] = (_Float16)fmaxf(acc[pj][i], 0.f);
    __syncthreads();
    #pragma unroll
    for (int it = 0; it < 2; ++it) {
        int l = t + it * 256;
        int row = l >> 3, s8 = l & 7;
        *(s16x8*)&recT[((long)b * NP + p0 + row) * CH + ct * 64 + s8 * 8] =
            *(const s16x8*)&rt[row * 80 + s8 * 8];
    }
}

// ---------------- fused EM loop + reconstruction (cooperative, 512 blocks) --
__global__ __launch_bounds__(256, 2) void em_loop(
    const _Float16* __restrict__ yT, const _Float16* __restrict__ y16,
    _Float16* __restrict__ muF, _Float16* __restrict__ zT,
    _Float16* __restrict__ z16, float* __restrict__ macc,
    float* __restrict__ zsum, float* __restrict__ mu_cur,
    _Float16* __restrict__ mu16, _Float16* __restrict__ recT)
{
    cg::grid_group gg = cg::this_grid();
    __shared__ float zred[256];
    __shared__ _Float16 rt[64 * 80];
    int g = blockIdx.x;      // 0..511
    int t = threadIdx.x;
    int w = t >> 6, lane = t & 63, l15 = lane & 15, l4 = lane >> 4;

    for (int s = 0; s < 5; ++s) {
        // ===== Z: 640 jobs, grid-stride 512 =====
        for (int job = g; job < 640; job += 512) {
            int b = job / 80;
            int p0 = (job % 80) * 64 + w * 16;
            float* zs = zsum + s * 512 + b * 64;
            const _Float16* mf = muF + ((long)b << 15);
            const _Float16* a0p = yT + ((long)b * NP + p0 + l15) * CH + l4 * 8;
            f32x4 acc[4];
            #pragma unroll
            for (int j = 0; j < 4; ++j) acc[j] = (f32x4){0.f, 0.f, 0.f, 0.f};
            #pragma unroll
            for (int cc = 0; cc < 16; ++cc) {
                f16x8 a0 = *(const f16x8*)(a0p + cc * 32);
                #pragma unroll
                for (int j = 0; j < 4; ++j) {
                    f16x8 bj = *(const f16x8*)&mf[(((cc * 4 + j) * 64) + lane) * 8];
                    acc[j] = __builtin_amdgcn_mfma_f32_16x16x32_f16(a0, bj, acc[j], 0, 0, 0);
                }
            }
            float zv[4][4];
            #pragma unroll
            for (int i = 0; i < 4; ++i) {
                float m = fmaxf(fmaxf(acc[0][i], acc[1][i]), fmaxf(acc[2][i], acc[3][i]));
                #pragma unroll
                for (int off = 1; off < 16; off <<= 1) m = fmaxf(m, __shfl_xor(m, off, 64));
                float e0 = __expf(acc[0][i] - m);
                float e1 = __expf(acc[1][i] - m);
                float e2 = __expf(acc[2][i] - m);
                float e3 = __expf(acc[3][i] - m);
                float ss = e0 + e1 + e2 + e3;
                #pragma unroll
                for (int off = 1; off < 16; off <<= 1) ss += __shfl_xor(ss, off, 64);
                float inv = 1.f / ss;
                zv[0][i] = e0 * inv; zv[1][i] = e1 * inv;
                zv[2][i] = e2 * inv; zv[3][i] = e3 * inv;
            }
            int prow = p0 + l4 * 4;
            long ztbase = (long)b * K * NP;
            #pragma unroll
            for (int j = 0; j < 4; ++j) {
                f16x4 pk = { (_Float16)zv[j][0], (_Float16)zv[j][1],
                             (_Float16)zv[j][2], (_Float16)zv[j][3] };
                *(f16x4*)&zT[ztbase + (long)(l15 + 16 * j) * NP + prow] = pk;
            }
            if (s == 4) {
                long zbase = (long)b * NP * K;
                #pragma unroll
                for (int j = 0; j < 4; ++j)
                    #pragma unroll
                    for (int i = 0; i < 4; ++i)
                        z16[zbase + (long)(prow + i) * K + l15 + 16 * j] = (_Float16)zv[j][i];
            }
            float part[4];
            #pragma unroll
            for (int j = 0; j < 4; ++j) {
                part[j] = zv[j][0] + zv[j][1] + zv[j][2] + zv[j][3];
                part[j] += __shfl_xor(part[j], 16, 64);
                part[j] += __shfl_xor(part[j], 32, 64);
            }
            if (l4 == 0) {
                #pragma unroll
                for (int j = 0; j < 4; ++j) zred[w * 64 + l15 + 16 * j] = part[j];
            }
            __syncthreads();
            if (t < 64)
                atomicAdd(&zs[t], zred[t] + zred[64 + t] + zred[128 + t] + zred[192 + t]);
            __syncthreads();   // protect zred for next job / next stage
        }
        gg.sync();
        // ===== MU: exactly 512 jobs =====
        {
            int b = g >> 6, r = g & 63, pc = r & 15, ct = r >> 4;
            int c0 = ct * 128 + w * 32;
            int pbase = pc * 320;
            const _Float16* zrow = zT + (long)b * K * NP + (long)l15 * NP + l4 * 8;
            const _Float16* a0p = y16 + ((long)b * CH + c0 + l15) * NP + l4 * 8;
            const _Float16* a1p = y16 + ((long)b * CH + c0 + 16 + l15) * NP + l4 * 8;
            f32x4 acc[2][4];
            #pragma unroll
            for (int ci = 0; ci < 2; ++ci)
                #pragma unroll
                for (int j = 0; j < 4; ++j) acc[ci][j] = (f32x4){0.f, 0.f, 0.f, 0.f};
            for (int p0 = pbase; p0 < pbase + 320; p0 += 32) {
                f16x8 a0 = *(const f16x8*)(a0p + p0);
                f16x8 a1 = *(const f16x8*)(a1p + p0);
                #pragma unroll
                for (int j = 0; j < 4; ++j) {
                    f16x8 bj = *(const f16x8*)(zrow + (long)(16 * j) * NP + p0);
                    acc[0][j] = __builtin_amdgcn_mfma_f32_16x16x32_f16(a0, bj, acc[0][j], 0, 0, 0);
                    acc[1][j] = __builtin_amdgcn_mfma_f32_16x16x32_f16(a1, bj, acc[1][j], 0, 0, 0);
                }
            }
            float* mp = macc + ((long)pc * BB + b) * K * CH;
            #pragma unroll
            for (int ci = 0; ci < 2; ++ci)
                #pragma unroll
                for (int j = 0; j < 4; ++j)
                    *(f32x4*)&mp[(long)(l15 + 16 * j) * CH + c0 + ci * 16 + l4 * 4] = acc[ci][j];
        }
        gg.sync();
        // ===== NORM: blocks 0..127 =====
        if (g < 128) {
            int gw = g * 4 + w;
            int b = gw >> 6, k = gw & 63;
            float v[8];
            float sq = 0.f;
            #pragma unroll
            for (int ci = 0; ci < 8; ++ci) {
                int c = ci * 64 + lane;
                float a = 0.f;
                #pragma unroll
                for (int pcc = 0; pcc < 16; ++pcc)
                    a += macc[(((long)pcc * BB + b) * K + k) * CH + c];
                v[ci] = a; sq += a * a;
            }
            #pragma unroll
            for (int off = 1; off < 64; off <<= 1) sq += __shfl_xor(sq, off, 64);
            float d = 1e-6f + zsum[s * 512 + b * 64 + k];
            float scale = 1.f / (1e-6f * d + sqrtf(sq));
            long mb = (long)b << 15;
            #pragma unroll
            for (int ci = 0; ci < 8; ++ci) {
                int c = ci * 64 + lane;
                float m = v[ci] * scale;
                mu_cur[mb + (long)c * K + k] = m;
                mu16[mb + (long)c * K + k] = (_Float16)m;
                muF[mufrag_idx(b, c, k)] = (_Float16)m;
            }
        }
        gg.sync();
    }

    // ===== REC: 640 jobs, grid-stride 512 =====
    for (int job = g; job < 640; job += 512) {
        int b = job / 80, p0 = (job % 80) * 64;
        const _Float16* zb = z16 + (long)b * NP * K;
        for (int ct = 0; ct < 8; ++ct) {
            __syncthreads();   // rt reuse across iterations/jobs
            const _Float16* mb = mu16 + ((long)b << 15)
                               + (long)(ct * 64 + w * 16 + l15) * K + l4 * 8;
            f32x4 acc[4];
            #pragma unroll
            for (int pj = 0; pj < 4; ++pj) acc[pj] = (f32x4){0.f, 0.f, 0.f, 0.f};
            #pragma unroll
            for (int kc = 0; kc < 64; kc += 32) {
                f16x8 bfr = *(const f16x8*)(mb + kc);
                #pragma unroll
                for (int pj = 0; pj < 4; ++pj) {
                    f16x8 a = *(const f16x8*)(zb + (long)(p0 + pj * 16 + l15) * K + kc + l4 * 8);
                    acc[pj] = __builtin_amdgcn_mfma_f32_16x16x32_f16(a, bfr, acc[pj], 0, 0, 0);
                }
            }
            #pragma unroll
            for (int pj = 0; pj < 4; ++pj)
                #pragma unroll
                for (int i = 0; i < 4; ++i)
                    rt[(pj * 16 + l4 * 4 + i) * 80 + w * 16 + l15] =
                        (_Float16)fmaxf(acc[pj][i], 0.f);
            __syncthreads();
            #pragma unroll
            for (int it = 0; it < 2; ++it) {
                int l = t + it * 256;
                int row = l >> 3, s8 = l & 7;
                *(s16x8*)&recT[((long)b * NP + p0 + row) * CH + ct * 64 + s8 * 8] =
                    *(const s16x8*)&rt[row * 80 + s8 * 8];
            }
        }
    }
}

// ---------------- BN stats: 1 block/channel, coalesced f16x4, no atomics ----
__global__ __launch_bounds__(256) void bn_stats2(const _Float16* __restrict__ y2h,
                                                 float* __restrict__ stats,
                                                 float* __restrict__ statsq)
{
    int d = blockIdx.x;
    int t = threadIdx.x;
    float s = 0.f, q = 0.f;
    for (int bi = 0; bi < BI; ++bi) {
        const _Float16* p = y2h + (long)bi * CH * HW + (long)d * HW;
        f16x4 v = *(const f16x4*)&p[t * 4];
        float v0 = (float)v[0], v1 = (float)v[1], v2 = (float)v[2], v3 = (float)v[3];
        s += v0 + v1 + v2 + v3;
        q += v0 * v0 + v1 * v1 + v2 * v2 + v3 * v3;
    }
    #pragma unroll
    for (int off = 1; off < 64; off <<= 1) {
        s += __shfl_xor(s, off, 64);
        q += __shfl_xor(q, off, 64);
    }
    __shared__ float ps[8];
    int wv = t >> 6, ln = t & 63;
    if (ln == 0) { ps[wv] = s; ps[4 + wv] = q; }
    __syncthreads();
    if (t == 0) {
        stats[d]  = ps[0] + ps[1] + ps[2] + ps[3];
        statsq[d] = ps[4] + ps[5] + ps[6] + ps[7];
    }
}

// ---------------- finale: BN + residual + relu, plus mu_b copy --------------
__global__ __launch_bounds__(256) void final_kernel(
    const _Float16* __restrict__ y2h, const float* __restrict__ x,
    const float* __restrict__ stats, const float* __restrict__ statsq,
    const float* __restrict__ gamma, const float* __restrict__ beta,
    const float* __restrict__ mu_cur, float* __restrict__ out)
{
    long i4 = (long)blockIdx.x * 256 + threadIdx.x;
    const long NMAIN4 = (long)BI * CH * HW / 4;     // 5242880
    if (i4 < NMAIN4) {
        long i = i4 * 4;
        int d = (int)((i >> 10) & (CH - 1));
        float s = stats[d], sq = statsq[d];
        const float inv = 1.f / (float)(BI * HW);
        float mean = s * inv;
        float var = sq * inv - mean * mean;
        float rs = rsqrtf(var + 1e-5f);
        float g = rs * gamma[d];
        float bb = beta[d] - mean * g;
        f16x4 yv = *(const f16x4*)&y2h[i];
        float4 xv = *(const float4*)&x[i];
        float4 ov;
        ov.x = fmaxf((float)yv[0] * g + bb + xv.x, 0.f);
        ov.y = fmaxf((float)yv[1] * g + bb + xv.y, 0.f);
        ov.z = fmaxf((float)yv[2] * g + bb + xv.z, 0.f);
        ov.w = fmaxf((float)yv[3] * g + bb + xv.w, 0.f);
        *(float4*)&out[i] = ov;
    } else {
        long j = (i4 - NMAIN4) * 4;                 // mu tail: 262144 elements
        *(float4*)&out[(long)BI * CH * HW + j] = *(const float4*)&mu_cur[j];
    }
}

extern "C" void kernel_launch(void* const* d_in, const int* in_sizes, int n_in,
                              void* d_out, int out_size, void* d_ws, size_t ws_size,
                              hipStream_t stream) {
    const float* x   = (const float*)d_in[0];
    const float* mu0 = (const float*)d_in[1];
    const float* w1  = (const float*)d_in[2];
    const float* b1  = (const float*)d_in[3];
    const float* w2  = (const float*)d_in[4];
    const float* gm  = (const float*)d_in[5];
    const float* bt  = (const float*)d_in[6];
    float* out = (float*)d_out;

    float* ws = (float*)d_ws;
    _Float16* y16h  = (_Float16*)(ws);              // [8][512][5120]
    _Float16* yT16h = (_Float16*)(ws + 10485760);   // [8][5120][512] (reused as recT)
    _Float16* xTh   = (_Float16*)(ws + 20971520);   // [40960][512]
    _Float16* zTh   = (_Float16*)(ws + 20971520);   // [8][64][5120] (reuses xT)
    _Float16* z16h  = (_Float16*)(ws + 22282240);   // [8][5120][64]
    _Float16* y2h   = (_Float16*)(ws + 20971520);   // [40][512][1024] (reuses zT/z16/macc)
    float*    macc  = ws + 23592960;                // [16][8][64][512]
    float*    mu_cur = ws + 31457280;               // 262,144 f
    _Float16* Wh1   = (_Float16*)(ws + 31719424);
    _Float16* Wh2   = (_Float16*)(ws + 31850496);
    _Float16* mu16h = (_Float16*)(ws + 31981568);
    _Float16* muFh  = (_Float16*)(ws + 32112640);
    float*    zsum  = ws + 32243712;                // [5][512]
    float*    stats = ws + 32246272;
    float*    statsq = ws + 32246784;

    hipMemsetAsync(zsum, 0, 2560 * sizeof(float), stream);

    wconv<<<1024, 256, 0, stream>>>(w1, Wh1);
    wconv<<<1024, 256, 0, stream>>>(w2, Wh2);
    transpose_f16<<<dim3(16, 8, 40), 256, 0, stream>>>(x, xTh, HW);
    conv_tile<<<1280, 256, 0, stream>>>(Wh1, xTh, b1, nullptr, y16h, yT16h, 0);
    bcast_mu2<<<1024, 256, 0, stream>>>(mu0, mu_cur, muFh);

    bool coop_ok = false;
    {
        const _Float16* yTp = yT16h;
        const _Float16* y16p = y16h;
        _Float16* muFp = muFh;
        _Float16* zTp = zTh;
        _Float16* z16p = z16h;
        float* maccp = macc;
        float* zsump = zsum;
        float* mucurp = mu_cur;
        _Float16* mu16p = mu16h;
        _Float16* recTp = yT16h;   // rec overwrites yT region (dead after last Z)
        void* args[] = { (void*)&yTp, (void*)&y16p, (void*)&muFp, (void*)&zTp,
                         (void*)&z16p, (void*)&maccp, (void*)&zsump, (void*)&mucurp,
                         (void*)&mu16p, (void*)&recTp };
        hipError_t cerr = hipLaunchCooperativeKernel((const void*)em_loop, dim3(512),
                                                     dim3(256), args, 0, stream);
        coop_ok = (cerr == hipSuccess);
    }
    if (!coop_ok) {
        // fallback: proven round-10 per-stage sequence (identical arithmetic)
        for (int s = 0; s < 5; ++s) {
            stage_z_mfma<<<dim3(80, 8), 256, 0, stream>>>(yT16h, muFh, zTh, z16h,
                                                          zsum + s * 512, s == 4);
            stage_mu_mfma<<<dim3(16, 4, 8), 256, 0, stream>>>(y16h, zTh, macc);
            mu_norm2<<<128, 256, 0, stream>>>(macc, zsum + s * 512, mu_cur, mu16h, muFh);
        }
        rec_mfma<<<dim3(80, 8, 8), 256, 0, stream>>>(z16h, mu16h, yT16h);
    }

    // conv2 writes fp16 y2 into the (now dead) zT/z16/macc region
    conv_tile<<<1280, 256, 0, stream>>>(Wh2, yT16h, nullptr, y2h, nullptr, nullptr, 1);
    bn_stats2<<<512, 256, 0, stream>>>(y2h, stats, statsq);
    long total4 = ((long)BI * CH * HW + (long)BB * CH * K) / 4;
    final_kernel<<<(int)((total4 + 255) / 256), 256, 0, stream>>>(
        y2h, x, stats, statsq, gm, bt, mu_cur, out);
}

// Round 13
// 474.135 us; speedup vs baseline: 3.4476x; 3.4476x over previous
//
#include <hip/hip_runtime.h>
#include <math.h>

#define CH 512
#define K 64
#define BB 8
#define NIMG 5
#define HW 1024
#define NP 5120   // NIMG*HW
#define BI 40     // BB*NIMG

typedef __attribute__((ext_vector_type(8))) _Float16 f16x8;
typedef __attribute__((ext_vector_type(4))) _Float16 f16x4;
typedef __attribute__((ext_vector_type(4))) float f32x4;
typedef __attribute__((ext_vector_type(8))) short s16x8;

#define AS1 __attribute__((address_space(1)))
#define AS3 __attribute__((address_space(3)))

// frag index for mu/B-operand: lane holds mu[k=l15+16j][c=cc*32+l4*8+e]
__device__ inline long mufrag_idx(int b, int c, int k) {
    int cc = c >> 5, l4 = (c >> 3) & 3, e = c & 7;
    int j = k >> 4, l15 = k & 15;
    int lane = l4 * 16 + l15;
    return ((long)b << 15) + (((cc * 4 + j) * 64 + lane) << 3) + e;
}

// ---------------- W fp32 -> fp16 (row-major copy) ---------------------------
__global__ __launch_bounds__(256) void wconv(const float* __restrict__ w,
                                             _Float16* __restrict__ o)
{
    int i = blockIdx.x * 256 + threadIdx.x;   // 262144
    o[i] = (_Float16)w[i];
}

// ---------------- transpose fp32 [z][512][P] -> fp16 [z][P][512] ------------
__global__ __launch_bounds__(256) void transpose_f16(
    const float* __restrict__ in, _Float16* __restrict__ out, int P)
{
    __shared__ float tile[64][65];
    int t = threadIdx.x;
    int p0 = blockIdx.x * 64, c0 = blockIdx.y * 64;
    long ibase = (long)blockIdx.z * CH * P;
    long obase = (long)blockIdx.z * P * CH;
    int pl = t & 63, chh = t >> 6;
    #pragma unroll
    for (int i = 0; i < 16; ++i)
        tile[chh + i * 4][pl] = in[ibase + (long)(c0 + chh + i * 4) * P + p0 + pl];
    __syncthreads();
    int cc = t & 31, pr = t >> 5;
    #pragma unroll
    for (int i = 0; i < 8; ++i) {
        int p = pr + i * 8;
        _Float16 lo = (_Float16)tile[cc * 2][p];
        _Float16 hi = (_Float16)tile[cc * 2 + 1][p];
        unsigned lob = (unsigned)*(unsigned short*)&lo;
        unsigned hib = (unsigned)*(unsigned short*)&hi;
        *(unsigned*)&out[obase + (long)(p0 + p) * CH + c0 + cc * 2] = lob | (hib << 16);
    }
}

// ---------------- broadcast mu -> mu_cur fp32 + muF frag-order fp16 ---------
__global__ __launch_bounds__(256) void bcast_mu2(const float* __restrict__ mu_in,
                                                 float* __restrict__ mu_cur,
                                                 _Float16* __restrict__ muF)
{
    int i = blockIdx.x * 256 + threadIdx.x;   // [b][c][k], 262144
    float v = mu_in[i & 32767];
    mu_cur[i] = v;
    int b = i >> 15, ck = i & 32767, c = ck >> 6, k = ck & 63;
    muF[mufrag_idx(b, c, k)] = (_Float16)v;
}

// ---------------- conv via single-buffer tiled MFMA + XCD swizzle -----------
__global__ __launch_bounds__(256) void conv_tile(
    const _Float16* __restrict__ Wh, const _Float16* __restrict__ inT,
    const float* __restrict__ bias, _Float16* __restrict__ y2h,
    _Float16* __restrict__ y16, _Float16* __restrict__ yT16, int mode)
{
    __shared__ _Float16 Wt[128 * 64];   // 16 KB
    __shared__ _Float16 Xt[128 * 64];   // 16 KB
    int t = threadIdx.x;
    int lane = t & 63, w = t >> 6;
    int l15 = lane & 15, l4 = lane >> 4;
    int wd = w & 1, wp = w >> 1;        // wave quadrant: 64d x 64p
    int sw = (blockIdx.x & 7) * 160 + (blockIdx.x >> 3);
    int px = sw & 7;            // p-tile
    int dy = (sw >> 3) & 3;     // d-tile
    int bi = sw >> 5;           // image
    int d0 = dy * 128;
    int pl0 = px * 128;
    long prow0 = (long)bi * HW + pl0;
    int ci_row = lane >> 3;
    int colb_phys = (lane & 7) * 16;

    f32x4 acc[4][4];
    #pragma unroll
    for (int ai = 0; ai < 4; ++ai)
        #pragma unroll
        for (int bj = 0; bj < 4; ++bj) acc[ai][bj] = (f32x4){0.f, 0.f, 0.f, 0.f};

    for (int c0 = 0; c0 < CH; c0 += 64) {
        __syncthreads();
        #pragma unroll
        for (int i = 0; i < 4; ++i) {
            int row = w * 32 + i * 8 + ci_row;
            int cb = colb_phys ^ ((row & 7) << 4);
            const _Float16* srcW = Wh + (long)(d0 + row) * CH + c0 + (cb >> 1);
            const _Float16* srcX = inT + (prow0 + row) * (long)CH + c0 + (cb >> 1);
            __builtin_amdgcn_global_load_lds((const AS1 void*)srcW,
                (AS3 void*)&Wt[(w * 32 + i * 8) * 64], 16, 0, 0);
            __builtin_amdgcn_global_load_lds((const AS1 void*)srcX,
                (AS3 void*)&Xt[(w * 32 + i * 8) * 64], 16, 0, 0);
        }
        __syncthreads();
        #pragma unroll
        for (int kk = 0; kk < 2; ++kk) {
            f16x8 af[4], bf[4];
            #pragma unroll
            for (int ai = 0; ai < 4; ++ai) {
                int row = wd * 64 + ai * 16 + l15;
                int cb = (kk * 64 + l4 * 16) ^ ((row & 7) << 4);
                af[ai] = *(const f16x8*)((const char*)Wt + row * 128 + cb);
            }
            #pragma unroll
            for (int bj = 0; bj < 4; ++bj) {
                int row = wp * 64 + bj * 16 + l15;
                int cb = (kk * 64 + l4 * 16) ^ ((row & 7) << 4);
                bf[bj] = *(const f16x8*)((const char*)Xt + row * 128 + cb);
            }
            #pragma unroll
            for (int ai = 0; ai < 4; ++ai)
                #pragma unroll
                for (int bj = 0; bj < 4; ++bj)
                    acc[ai][bj] = __builtin_amdgcn_mfma_f32_16x16x32_f16(
                        af[ai], bf[bj], acc[ai][bj], 0, 0, 0);
        }
    }

    int b = bi / NIMG, n = bi % NIMG;
    if (mode == 0) {
        #pragma unroll
        for (int ai = 0; ai < 4; ++ai) {
            int dd = d0 + wd * 64 + ai * 16 + l4 * 4;
            float b0 = bias[dd], b1 = bias[dd + 1], b2 = bias[dd + 2], b3 = bias[dd + 3];
            #pragma unroll
            for (int bj = 0; bj < 4; ++bj) {
                int pb = n * HW + pl0 + wp * 64 + bj * 16 + l15;
                f16x4 pk = { (_Float16)(acc[ai][bj][0] + b0), (_Float16)(acc[ai][bj][1] + b1),
                             (_Float16)(acc[ai][bj][2] + b2), (_Float16)(acc[ai][bj][3] + b3) };
                *(f16x4*)&yT16[((long)b * NP + pb) * CH + dd] = pk;
                long yb = ((long)b * CH + dd) * NP + pb;
                y16[yb] = pk[0];
                y16[yb + NP] = pk[1];
                y16[yb + 2 * NP] = pk[2];
                y16[yb + 3 * NP] = pk[3];
            }
        }
    } else {
        long obase = (long)bi * CH * HW;
        #pragma unroll
        for (int ai = 0; ai < 4; ++ai) {
            int dd = d0 + wd * 64 + ai * 16 + l4 * 4;
            #pragma unroll
            for (int bj = 0; bj < 4; ++bj) {
                int p = pl0 + wp * 64 + bj * 16 + l15;
                long o = obase + (long)dd * HW + p;
                y2h[o] = (_Float16)acc[ai][bj][0];
                y2h[o + HW] = (_Float16)acc[ai][bj][1];
                y2h[o + 2 * HW] = (_Float16)acc[ai][bj][2];
                y2h[o + 3 * HW] = (_Float16)acc[ai][bj][3];
            }
        }
    }
}

// ---------------- fused Z+MU per stage: one block = (128 p, one b) ----------
// grid (40, 8). Z: softmax scores for 128 p (wave w owns 32 p); z staged into
// LDS in MFMA B-frag order. MU: each wave owns 128 c x 64 k over those 128 p;
// writes fp32 partial slot maccP[pc][b][k][c]. zsum via atomics. z16 on s==4.
__global__ __launch_bounds__(256) void zmu_fused(
    const _Float16* __restrict__ yT, const _Float16* __restrict__ y16,
    const _Float16* __restrict__ muF, _Float16* __restrict__ z16,
    float* __restrict__ maccP, float* __restrict__ zsum, int writeZ)
{
    __shared__ _Float16 zf[4 * 4 * 64 * 8];   // [pstep][j][lane'][e] = 16 KB
    __shared__ float zred[256];
    int t = threadIdx.x;
    int w = t >> 6, lane = t & 63, l15 = lane & 15, l4 = lane >> 4;
    int pc = blockIdx.x, b = blockIdx.y;
    int pblock0 = pc * 128;
    int p0 = pblock0 + w * 32;

    // ===== Z phase (round-7 proven pattern: 2 A-rows per wave) =====
    const _Float16* mf = muF + ((long)b << 15);
    const _Float16* a0p = yT + ((long)b * NP + p0 + l15) * CH + l4 * 8;
    const _Float16* a1p = yT + ((long)b * NP + p0 + 16 + l15) * CH + l4 * 8;
    f32x4 acc[2][4];
    #pragma unroll
    for (int pb = 0; pb < 2; ++pb)
        #pragma unroll
        for (int j = 0; j < 4; ++j) acc[pb][j] = (f32x4){0.f, 0.f, 0.f, 0.f};
    #pragma unroll
    for (int cc = 0; cc < 16; ++cc) {
        f16x8 a0 = *(const f16x8*)(a0p + cc * 32);
        f16x8 a1 = *(const f16x8*)(a1p + cc * 32);
        #pragma unroll
        for (int j = 0; j < 4; ++j) {
            f16x8 bj = *(const f16x8*)&mf[(((cc * 4 + j) * 64) + lane) * 8];
            acc[0][j] = __builtin_amdgcn_mfma_f32_16x16x32_f16(a0, bj, acc[0][j], 0, 0, 0);
            acc[1][j] = __builtin_amdgcn_mfma_f32_16x16x32_f16(a1, bj, acc[1][j], 0, 0, 0);
        }
    }
    float part[4] = {0.f, 0.f, 0.f, 0.f};
    long zbase = (long)b * NP * K;
    #pragma unroll
    for (int pb = 0; pb < 2; ++pb) {
        float zv[4][4];
        #pragma unroll
        for (int i = 0; i < 4; ++i) {
            float m = fmaxf(fmaxf(acc[pb][0][i], acc[pb][1][i]),
                            fmaxf(acc[pb][2][i], acc[pb][3][i]));
            #pragma unroll
            for (int off = 1; off < 16; off <<= 1) m = fmaxf(m, __shfl_xor(m, off, 64));
            float e0 = __expf(acc[pb][0][i] - m);
            float e1 = __expf(acc[pb][1][i] - m);
            float e2 = __expf(acc[pb][2][i] - m);
            float e3 = __expf(acc[pb][3][i] - m);
            float ss = e0 + e1 + e2 + e3;
            #pragma unroll
            for (int off = 1; off < 16; off <<= 1) ss += __shfl_xor(ss, off, 64);
            float inv = 1.f / ss;
            zv[0][i] = e0 * inv; zv[1][i] = e1 * inv;
            zv[2][i] = e2 * inv; zv[3][i] = e3 * inv;
        }
        // LDS store in B-frag order: z[p = pstep*32 + l4'*8 + e][k = l15' + 16j]
        // source p_local&31 = pb*16 + l4*4 + i  ->  lane' = (pb*2+(l4>>1))*16+l15,
        // e = (l4&1)*4 + i  (4 consecutive halfwords -> one f16x4 store)
        int lanep = (pb * 2 + (l4 >> 1)) * 16 + l15;
        int e0i = (l4 & 1) * 4;
        #pragma unroll
        for (int j = 0; j < 4; ++j) {
            f16x4 pk = { (_Float16)zv[j][0], (_Float16)zv[j][1],
                         (_Float16)zv[j][2], (_Float16)zv[j][3] };
            *(f16x4*)&zf[(((w * 4 + j) * 64 + lanep) << 3) + e0i] = pk;
        }
        if (writeZ) {
            int prow = p0 + pb * 16 + l4 * 4;
            #pragma unroll
            for (int j = 0; j < 4; ++j)
                #pragma unroll
                for (int i = 0; i < 4; ++i)
                    z16[zbase + (long)(prow + i) * K + l15 + 16 * j] = (_Float16)zv[j][i];
        }
        #pragma unroll
        for (int j = 0; j < 4; ++j)
            part[j] += zv[j][0] + zv[j][1] + zv[j][2] + zv[j][3];
    }
    #pragma unroll
    for (int j = 0; j < 4; ++j) {
        part[j] += __shfl_xor(part[j], 16, 64);
        part[j] += __shfl_xor(part[j], 32, 64);
    }
    if (l4 == 0) {
        #pragma unroll
        for (int j = 0; j < 4; ++j) zred[w * 64 + l15 + 16 * j] = part[j];
    }
    __syncthreads();   // zf + zred complete; MU may read all psteps
    if (t < 64)
        atomicAdd(&zsum[b * 64 + t], zred[t] + zred[64 + t] + zred[128 + t] + zred[192 + t]);

    // ===== MU phase: wave w owns c = w*128 .. +127; K-dim = this block's 128 p
    const _Float16* ybase = y16 + ((long)b * CH + w * 128 + l15) * NP + pblock0 + l4 * 8;
    f32x4 macc_r[8][4];
    #pragma unroll
    for (int r = 0; r < 8; ++r)
        #pragma unroll
        for (int j = 0; j < 4; ++j) macc_r[r][j] = (f32x4){0.f, 0.f, 0.f, 0.f};
    #pragma unroll
    for (int ps = 0; ps < 4; ++ps) {
        f16x8 bfr[4];
        #pragma unroll
        for (int j = 0; j < 4; ++j)
            bfr[j] = *(const f16x8*)&zf[((ps * 4 + j) * 64 + lane) << 3];
        #pragma unroll
        for (int r = 0; r < 8; ++r) {
            f16x8 a = *(const f16x8*)(ybase + (long)(r * 16) * NP + ps * 32);
            #pragma unroll
            for (int j = 0; j < 4; ++j)
                macc_r[r][j] = __builtin_amdgcn_mfma_f32_16x16x32_f16(
                    a, bfr[j], macc_r[r][j], 0, 0, 0);
        }
    }
    // D: row (A) = c = w*128 + r*16 + l4*4 + i, col (B) = k = l15 + 16j
    float* mp = maccP + ((long)pc * BB + b) * K * CH;
    #pragma unroll
    for (int r = 0; r < 8; ++r)
        #pragma unroll
        for (int j = 0; j < 4; ++j)
            *(f32x4*)&mp[(long)(l15 + 16 * j) * CH + w * 128 + r * 16 + l4 * 4] = macc_r[r][j];
}

// ---------------- mu normalize: sum 40 partials, l2norm, emit formats -------
__global__ __launch_bounds__(256) void mu_norm3(
    const float* __restrict__ maccP, const float* __restrict__ zsum,
    float* __restrict__ mu_cur, _Float16* __restrict__ mu16,
    _Float16* __restrict__ muF)
{
    int gw = blockIdx.x * 4 + (threadIdx.x >> 6);   // 512 = 8b x 64k
    int lane = threadIdx.x & 63;
    int b = gw >> 6, k = gw & 63;
    float v[8];
    float s = 0.f;
    #pragma unroll
    for (int ci = 0; ci < 8; ++ci) {
        int c = ci * 64 + lane;
        float a = 0.f;
        for (int pcc = 0; pcc < 40; ++pcc)
            a += maccP[(((long)pcc * BB + b) * K + k) * CH + c];
        v[ci] = a; s += a * a;
    }
    #pragma unroll
    for (int off = 1; off < 64; off <<= 1) s += __shfl_xor(s, off, 64);
    float d = 1e-6f + zsum[b * 64 + k];
    float scale = 1.f / (1e-6f * d + sqrtf(s));
    long mb = (long)b << 15;
    #pragma unroll
    for (int ci = 0; ci < 8; ++ci) {
        int c = ci * 64 + lane;
        float m = v[ci] * scale;
        mu_cur[mb + (long)c * K + k] = m;
        mu16[mb + (long)c * K + k] = (_Float16)m;
        muF[mufrag_idx(b, c, k)] = (_Float16)m;
    }
}

// ---------------- rec: recT[p][c] = relu(sum_k z16[p][k]*mu16[c][k]) --------
__global__ __launch_bounds__(256) void rec_mfma(
    const _Float16* __restrict__ z16, const _Float16* __restrict__ mu16,
    _Float16* __restrict__ recT)
{
    __shared__ _Float16 rt[64 * 80];
    int t = threadIdx.x;
    int w = t >> 6, lane = t & 63, l15 = lane & 15, l4 = lane >> 4;
    int p0 = blockIdx.x * 64, ct = blockIdx.y, b = blockIdx.z;
    const _Float16* zb = z16 + (long)b * NP * K;
    const _Float16* mb = mu16 + ((long)b << 15) + (long)(ct * 64 + w * 16 + l15) * K + l4 * 8;
    f32x4 acc[4];
    #pragma unroll
    for (int pj = 0; pj < 4; ++pj) acc[pj] = (f32x4){0.f, 0.f, 0.f, 0.f};
    #pragma unroll
    for (int kc = 0; kc < 64; kc += 32) {
        f16x8 bfr = *(const f16x8*)(mb + kc);
        #pragma unroll
        for (int pj = 0; pj < 4; ++pj) {
            f16x8 a = *(const f16x8*)(zb + (long)(p0 + pj * 16 + l15) * K + kc + l4 * 8);
            acc[pj] = __builtin_amdgcn_mfma_f32_16x16x32_f16(a, bfr, acc[pj], 0, 0, 0);
        }
    }
    #pragma unroll
    for (int pj = 0; pj < 4; ++pj)
        #pragma unroll
        for (int i = 0; i < 4; ++i)
            rt[(pj * 16 + l4 * 4 + i) * 80 + w * 16 + l15] = (_Float16)fmaxf(acc[pj][i], 0.f);
    __syncthreads();
    #pragma unroll
    for (int it = 0; it < 2; ++it) {
        int l = t + it * 256;
        int row = l >> 3, s8 = l & 7;
        *(s16x8*)&recT[((long)b * NP + p0 + row) * CH + ct * 64 + s8 * 8] =
            *(const s16x8*)&rt[row * 80 + s8 * 8];
    }
}

// ---------------- BN stats: 1 block/channel, coalesced f16x4, no atomics ----
__global__ __launch_bounds__(256) void bn_stats2(const _Float16* __restrict__ y2h,
                                                 float* __restrict__ stats,
                                                 float* __restrict__ statsq)
{
    int d = blockIdx.x;
    int t = threadIdx.x;
    float s = 0.f, q = 0.f;
    for (int bi = 0; bi < BI; ++bi) {
        const _Float16* p = y2h + (long)bi * CH * HW + (long)d * HW;
        f16x4 v = *(const f16x4*)&p[t * 4];
        float v0 = (float)v[0], v1 = (float)v[1], v2 = (float)v[2], v3 = (float)v[3];
        s += v0 + v1 + v2 + v3;
        q += v0 * v0 + v1 * v1 + v2 * v2 + v3 * v3;
    }
    #pragma unroll
    for (int off = 1; off < 64; off <<= 1) {
        s += __shfl_xor(s, off, 64);
        q += __shfl_xor(q, off, 64);
    }
    __shared__ float ps[8];
    int wv = t >> 6, ln = t & 63;
    if (ln == 0) { ps[wv] = s; ps[4 + wv] = q; }
    __syncthreads();
    if (t == 0) {
        stats[d]  = ps[0] + ps[1] + ps[2] + ps[3];
        statsq[d] = ps[4] + ps[5] + ps[6] + ps[7];
    }
}

// ---------------- finale: BN + residual + relu, plus mu_b copy --------------
__global__ __launch_bounds__(256) void final_kernel(
    const _Float16* __restrict__ y2h, const float* __restrict__ x,
    const float* __restrict__ stats, const float* __restrict__ statsq,
    const float* __restrict__ gamma, const float* __restrict__ beta,
    const float* __restrict__ mu_cur, float* __restrict__ out)
{
    long i4 = (long)blockIdx.x * 256 + threadIdx.x;
    const long NMAIN4 = (long)BI * CH * HW / 4;     // 5242880
    if (i4 < NMAIN4) {
        long i = i4 * 4;
        int d = (int)((i >> 10) & (CH - 1));
        float s = stats[d], sq = statsq[d];
        const float inv = 1.f / (float)(BI * HW);
        float mean = s * inv;
        float var = sq * inv - mean * mean;
        float rs = rsqrtf(var + 1e-5f);
        float g = rs * gamma[d];
        float bb = beta[d] - mean * g;
        f16x4 yv = *(const f16x4*)&y2h[i];
        float4 xv = *(const float4*)&x[i];
        float4 ov;
        ov.x = fmaxf((float)yv[0] * g + bb + xv.x, 0.f);
        ov.y = fmaxf((float)yv[1] * g + bb + xv.y, 0.f);
        ov.z = fmaxf((float)yv[2] * g + bb + xv.z, 0.f);
        ov.w = fmaxf((float)yv[3] * g + bb + xv.w, 0.f);
        *(float4*)&out[i] = ov;
    } else {
        long j = (i4 - NMAIN4) * 4;                 // mu tail: 262144 elements
        *(float4*)&out[(long)BI * CH * HW + j] = *(const float4*)&mu_cur[j];
    }
}

extern "C" void kernel_launch(void* const* d_in, const int* in_sizes, int n_in,
                              void* d_out, int out_size, void* d_ws, size_t ws_size,
                              hipStream_t stream) {
    const float* x   = (const float*)d_in[0];
    const float* mu0 = (const float*)d_in[1];
    const float* w1  = (const float*)d_in[2];
    const float* b1  = (const float*)d_in[3];
    const float* w2  = (const float*)d_in[4];
    const float* gm  = (const float*)d_in[5];
    const float* bt  = (const float*)d_in[6];
    float* out = (float*)d_out;

    float* ws = (float*)d_ws;
    _Float16* y16h  = (_Float16*)(ws);              // [8][512][5120]  10.49M f
    _Float16* yT16h = (_Float16*)(ws + 10485760);   // [8][5120][512]  (reused as recT)
    _Float16* xTh   = (_Float16*)(ws + 20971520);   // [40960][512]    10.49M f
    float*    maccP = ws + 20971520;                // [40][8][64][512] 10.49M f (reuses xT)
    _Float16* y2h   = (_Float16*)(ws + 20971520);   // [40][512][1024] (reuses maccP)
    float*    mu_cur = ws + 31457280;               // 262,144 f
    _Float16* Wh1   = (_Float16*)(ws + 31719424);
    _Float16* Wh2   = (_Float16*)(ws + 31850496);
    _Float16* mu16h = (_Float16*)(ws + 31981568);
    _Float16* muFh  = (_Float16*)(ws + 32112640);
    float*    zsum  = ws + 32243712;                // [5][512]
    float*    stats = ws + 32246272;
    float*    statsq = ws + 32246784;
    _Float16* z16h  = (_Float16*)(ws + 32247296);   // [8][5120][64] 1.31M f (tail)

    hipMemsetAsync(zsum, 0, 2560 * sizeof(float), stream);

    wconv<<<1024, 256, 0, stream>>>(w1, Wh1);
    wconv<<<1024, 256, 0, stream>>>(w2, Wh2);
    transpose_f16<<<dim3(16, 8, 40), 256, 0, stream>>>(x, xTh, HW);
    conv_tile<<<1280, 256, 0, stream>>>(Wh1, xTh, b1, nullptr, y16h, yT16h, 0);
    bcast_mu2<<<1024, 256, 0, stream>>>(mu0, mu_cur, muFh);

    for (int s = 0; s < 5; ++s) {
        zmu_fused<<<dim3(40, 8), 256, 0, stream>>>(yT16h, y16h, muFh, z16h,
                                                   maccP, zsum + s * 512, s == 4);
        mu_norm3<<<128, 256, 0, stream>>>(maccP, zsum + s * 512, mu_cur, mu16h, muFh);
    }

    // rec overwrites yT16 region (dead after last Z phase)
    rec_mfma<<<dim3(80, 8, 8), 256, 0, stream>>>(z16h, mu16h, yT16h);
    // conv2 writes fp16 y2 into the (now dead) maccP/xT region
    conv_tile<<<1280, 256, 0, stream>>>(Wh2, yT16h, nullptr, y2h, nullptr, nullptr, 1);
    bn_stats2<<<512, 256, 0, stream>>>(y2h, stats, statsq);
    long total4 = ((long)BI * CH * HW + (long)BB * CH * K) / 4;
    final_kernel<<<(int)((total4 + 255) / 256), 256, 0, stream>>>(
        y2h, x, stats, statsq, gm, bt, mu_cur, out);
}

// Round 14
// 400.434 us; speedup vs baseline: 4.0822x; 1.1841x over previous
//
#include <hip/hip_runtime.h>
#include <math.h>

#define CH 512
#define K 64
#define BB 8
#define NIMG 5
#define HW 1024
#define NP 5120   // NIMG*HW
#define BI 40     // BB*NIMG

typedef __attribute__((ext_vector_type(8))) _Float16 f16x8;
typedef __attribute__((ext_vector_type(4))) _Float16 f16x4;
typedef __attribute__((ext_vector_type(4))) float f32x4;
typedef __attribute__((ext_vector_type(8))) short s16x8;

#define AS1 __attribute__((address_space(1)))
#define AS3 __attribute__((address_space(3)))

// frag index for mu/B-operand: lane holds mu[k=l15+16j][c=cc*32+l4*8+e]
__device__ inline long mufrag_idx(int b, int c, int k) {
    int cc = c >> 5, l4 = (c >> 3) & 3, e = c & 7;
    int j = k >> 4, l15 = k & 15;
    int lane = l4 * 16 + l15;
    return ((long)b << 15) + (((cc * 4 + j) * 64 + lane) << 3) + e;
}

// ---------------- fused setup: Wh1, Wh2, mu bcast, zero-fill ----------------
__global__ __launch_bounds__(256) void setup_kernel(
    const float* __restrict__ w1, const float* __restrict__ w2,
    const float* __restrict__ mu_in, _Float16* __restrict__ Wh1,
    _Float16* __restrict__ Wh2, float* __restrict__ mu_cur,
    _Float16* __restrict__ muF, float* __restrict__ zerobuf)
{
    int i = blockIdx.x * 256 + threadIdx.x;
    if (i < 262144) {
        Wh1[i] = (_Float16)w1[i];
        Wh2[i] = (_Float16)w2[i];
        float v = mu_in[i & 32767];
        mu_cur[i] = v;
        int b = i >> 15, ck = i & 32767, c = ck >> 6, k = ck & 63;
        muF[mufrag_idx(b, c, k)] = (_Float16)v;
    } else if (i < 262144 + 3584) {
        zerobuf[i - 262144] = 0.f;   // zsum[5][512] + stats + statsq
    }
}

// ---------------- transpose fp32 [z][512][P] -> fp16 [z][P][512] ------------
__global__ __launch_bounds__(256) void transpose_f16(
    const float* __restrict__ in, _Float16* __restrict__ out, int P)
{
    __shared__ float tile[64][65];
    int t = threadIdx.x;
    int p0 = blockIdx.x * 64, c0 = blockIdx.y * 64;
    long ibase = (long)blockIdx.z * CH * P;
    long obase = (long)blockIdx.z * P * CH;
    int pl = t & 63, chh = t >> 6;
    #pragma unroll
    for (int i = 0; i < 16; ++i)
        tile[chh + i * 4][pl] = in[ibase + (long)(c0 + chh + i * 4) * P + p0 + pl];
    __syncthreads();
    int cc = t & 31, pr = t >> 5;
    #pragma unroll
    for (int i = 0; i < 8; ++i) {
        int p = pr + i * 8;
        _Float16 lo = (_Float16)tile[cc * 2][p];
        _Float16 hi = (_Float16)tile[cc * 2 + 1][p];
        unsigned lob = (unsigned)*(unsigned short*)&lo;
        unsigned hib = (unsigned)*(unsigned short*)&hi;
        *(unsigned*)&out[obase + (long)(p0 + p) * CH + c0 + cc * 2] = lob | (hib << 16);
    }
}

// ---------------- conv via single-buffer tiled MFMA + XCD swizzle -----------
__global__ __launch_bounds__(256) void conv_tile(
    const _Float16* __restrict__ Wh, const _Float16* __restrict__ inT,
    const float* __restrict__ bias, _Float16* __restrict__ y2h,
    _Float16* __restrict__ y16, _Float16* __restrict__ yT16, int mode)
{
    __shared__ _Float16 Wt[128 * 64];   // 16 KB
    __shared__ _Float16 Xt[128 * 64];   // 16 KB
    int t = threadIdx.x;
    int lane = t & 63, w = t >> 6;
    int l15 = lane & 15, l4 = lane >> 4;
    int wd = w & 1, wp = w >> 1;        // wave quadrant: 64d x 64p
    int sw = (blockIdx.x & 7) * 160 + (blockIdx.x >> 3);
    int px = sw & 7;            // p-tile
    int dy = (sw >> 3) & 3;     // d-tile
    int bi = sw >> 5;           // image
    int d0 = dy * 128;
    int pl0 = px * 128;
    long prow0 = (long)bi * HW + pl0;
    int ci_row = lane >> 3;
    int colb_phys = (lane & 7) * 16;

    f32x4 acc[4][4];
    #pragma unroll
    for (int ai = 0; ai < 4; ++ai)
        #pragma unroll
        for (int bj = 0; bj < 4; ++bj) acc[ai][bj] = (f32x4){0.f, 0.f, 0.f, 0.f};

    for (int c0 = 0; c0 < CH; c0 += 64) {
        __syncthreads();
        #pragma unroll
        for (int i = 0; i < 4; ++i) {
            int row = w * 32 + i * 8 + ci_row;
            int cb = colb_phys ^ ((row & 7) << 4);
            const _Float16* srcW = Wh + (long)(d0 + row) * CH + c0 + (cb >> 1);
            const _Float16* srcX = inT + (prow0 + row) * (long)CH + c0 + (cb >> 1);
            __builtin_amdgcn_global_load_lds((const AS1 void*)srcW,
                (AS3 void*)&Wt[(w * 32 + i * 8) * 64], 16, 0, 0);
            __builtin_amdgcn_global_load_lds((const AS1 void*)srcX,
                (AS3 void*)&Xt[(w * 32 + i * 8) * 64], 16, 0, 0);
        }
        __syncthreads();
        #pragma unroll
        for (int kk = 0; kk < 2; ++kk) {
            f16x8 af[4], bf[4];
            #pragma unroll
            for (int ai = 0; ai < 4; ++ai) {
                int row = wd * 64 + ai * 16 + l15;
                int cb = (kk * 64 + l4 * 16) ^ ((row & 7) << 4);
                af[ai] = *(const f16x8*)((const char*)Wt + row * 128 + cb);
            }
            #pragma unroll
            for (int bj = 0; bj < 4; ++bj) {
                int row = wp * 64 + bj * 16 + l15;
                int cb = (kk * 64 + l4 * 16) ^ ((row & 7) << 4);
                bf[bj] = *(const f16x8*)((const char*)Xt + row * 128 + cb);
            }
            #pragma unroll
            for (int ai = 0; ai < 4; ++ai)
                #pragma unroll
                for (int bj = 0; bj < 4; ++bj)
                    acc[ai][bj] = __builtin_amdgcn_mfma_f32_16x16x32_f16(
                        af[ai], bf[bj], acc[ai][bj], 0, 0, 0);
        }
    }

    int b = bi / NIMG, n = bi % NIMG;
    if (mode == 0) {
        #pragma unroll
        for (int ai = 0; ai < 4; ++ai) {
            int dd = d0 + wd * 64 + ai * 16 + l4 * 4;
            float b0 = bias[dd], b1 = bias[dd + 1], b2 = bias[dd + 2], b3 = bias[dd + 3];
            #pragma unroll
            for (int bj = 0; bj < 4; ++bj) {
                int pb = n * HW + pl0 + wp * 64 + bj * 16 + l15;
                f16x4 pk = { (_Float16)(acc[ai][bj][0] + b0), (_Float16)(acc[ai][bj][1] + b1),
                             (_Float16)(acc[ai][bj][2] + b2), (_Float16)(acc[ai][bj][3] + b3) };
                *(f16x4*)&yT16[((long)b * NP + pb) * CH + dd] = pk;
                long yb = ((long)b * CH + dd) * NP + pb;
                y16[yb] = pk[0];
                y16[yb + NP] = pk[1];
                y16[yb + 2 * NP] = pk[2];
                y16[yb + 3 * NP] = pk[3];
            }
        }
    } else {
        long obase = (long)bi * CH * HW;
        #pragma unroll
        for (int ai = 0; ai < 4; ++ai) {
            int dd = d0 + wd * 64 + ai * 16 + l4 * 4;
            #pragma unroll
            for (int bj = 0; bj < 4; ++bj) {
                int p = pl0 + wp * 64 + bj * 16 + l15;
                long o = obase + (long)dd * HW + p;
                y2h[o] = (_Float16)acc[ai][bj][0];
                y2h[o + HW] = (_Float16)acc[ai][bj][1];
                y2h[o + 2 * HW] = (_Float16)acc[ai][bj][2];
                y2h[o + 3 * HW] = (_Float16)acc[ai][bj][3];
            }
        }
    }
}

// ---------------- EM: S=yT*muF (MFMA, no LDS) + softmax + zT/z16/zsum -------
// grid (80, 8); wave w owns p = bx*64 + w*16 .. +15 (1 A-frag row, 64 MFMA).
__global__ __launch_bounds__(256) void stage_z_mfma(
    const _Float16* __restrict__ yT, const _Float16* __restrict__ muF,
    _Float16* __restrict__ zT, _Float16* __restrict__ z16,
    float* __restrict__ zsum, int writeZ)
{
    __shared__ float zred[256];
    int t = threadIdx.x;
    int w = t >> 6, lane = t & 63, l15 = lane & 15, l4 = lane >> 4;
    int p0 = blockIdx.x * 64 + w * 16;
    int b = blockIdx.y;
    const _Float16* mf = muF + ((long)b << 15);
    const _Float16* a0p = yT + ((long)b * NP + p0 + l15) * CH + l4 * 8;
    f32x4 acc[4];
    #pragma unroll
    for (int j = 0; j < 4; ++j) acc[j] = (f32x4){0.f, 0.f, 0.f, 0.f};
    #pragma unroll
    for (int cc = 0; cc < 16; ++cc) {
        f16x8 a0 = *(const f16x8*)(a0p + cc * 32);
        #pragma unroll
        for (int j = 0; j < 4; ++j) {
            f16x8 bj = *(const f16x8*)&mf[(((cc * 4 + j) * 64) + lane) * 8];
            acc[j] = __builtin_amdgcn_mfma_f32_16x16x32_f16(a0, bj, acc[j], 0, 0, 0);
        }
    }
    float zv[4][4];
    #pragma unroll
    for (int i = 0; i < 4; ++i) {
        float m = fmaxf(fmaxf(acc[0][i], acc[1][i]), fmaxf(acc[2][i], acc[3][i]));
        #pragma unroll
        for (int off = 1; off < 16; off <<= 1) m = fmaxf(m, __shfl_xor(m, off, 64));
        float e0 = __expf(acc[0][i] - m);
        float e1 = __expf(acc[1][i] - m);
        float e2 = __expf(acc[2][i] - m);
        float e3 = __expf(acc[3][i] - m);
        float s = e0 + e1 + e2 + e3;
        #pragma unroll
        for (int off = 1; off < 16; off <<= 1) s += __shfl_xor(s, off, 64);
        float inv = 1.f / s;
        zv[0][i] = e0 * inv; zv[1][i] = e1 * inv;
        zv[2][i] = e2 * inv; zv[3][i] = e3 * inv;
    }
    int prow = p0 + l4 * 4;
    long ztbase = (long)b * K * NP;
    #pragma unroll
    for (int j = 0; j < 4; ++j) {
        f16x4 pk = { (_Float16)zv[j][0], (_Float16)zv[j][1],
                     (_Float16)zv[j][2], (_Float16)zv[j][3] };
        *(f16x4*)&zT[ztbase + (long)(l15 + 16 * j) * NP + prow] = pk;
    }
    if (writeZ) {
        long zbase = (long)b * NP * K;
        #pragma unroll
        for (int j = 0; j < 4; ++j)
            #pragma unroll
            for (int i = 0; i < 4; ++i)
                z16[zbase + (long)(prow + i) * K + l15 + 16 * j] = (_Float16)zv[j][i];
    }
    float part[4];
    #pragma unroll
    for (int j = 0; j < 4; ++j) {
        part[j] = zv[j][0] + zv[j][1] + zv[j][2] + zv[j][3];
        part[j] += __shfl_xor(part[j], 16, 64);
        part[j] += __shfl_xor(part[j], 32, 64);
    }
    if (l4 == 0) {
        #pragma unroll
        for (int j = 0; j < 4; ++j) zred[w * 64 + l15 + 16 * j] = part[j];
    }
    __syncthreads();
    if (t < 64)
        atomicAdd(&zsum[b * 64 + t], zred[t] + zred[64 + t] + zred[128 + t] + zred[192 + t]);
}

// ---------------- EM: macc[pc][b][k][c] = sum_p y16[c][p]*zT[k][p] ----------
// grid (16 pc, 4 ct, 8 b); wave w owns c = ct*128 + w*32 .. +31; no LDS.
__global__ __launch_bounds__(256) void stage_mu_mfma(
    const _Float16* __restrict__ y16, const _Float16* __restrict__ zT,
    float* __restrict__ macc)
{
    int t = threadIdx.x;
    int w = t >> 6, lane = t & 63, l15 = lane & 15, l4 = lane >> 4;
    int pc = blockIdx.x, ct = blockIdx.y, b = blockIdx.z;
    int c0 = ct * 128 + w * 32;
    int pbase = pc * 320;
    const _Float16* zrow = zT + (long)b * K * NP + (long)l15 * NP + l4 * 8;
    const _Float16* a0p = y16 + ((long)b * CH + c0 + l15) * NP + l4 * 8;
    const _Float16* a1p = y16 + ((long)b * CH + c0 + 16 + l15) * NP + l4 * 8;
    f32x4 acc[2][4];
    #pragma unroll
    for (int ci = 0; ci < 2; ++ci)
        #pragma unroll
        for (int j = 0; j < 4; ++j) acc[ci][j] = (f32x4){0.f, 0.f, 0.f, 0.f};
    for (int p0 = pbase; p0 < pbase + 320; p0 += 32) {
        f16x8 a0 = *(const f16x8*)(a0p + p0);
        f16x8 a1 = *(const f16x8*)(a1p + p0);
        #pragma unroll
        for (int j = 0; j < 4; ++j) {
            f16x8 bj = *(const f16x8*)(zrow + (long)(16 * j) * NP + p0);
            acc[0][j] = __builtin_amdgcn_mfma_f32_16x16x32_f16(a0, bj, acc[0][j], 0, 0, 0);
            acc[1][j] = __builtin_amdgcn_mfma_f32_16x16x32_f16(a1, bj, acc[1][j], 0, 0, 0);
        }
    }
    float* mp = macc + ((long)pc * BB + b) * K * CH;
    #pragma unroll
    for (int ci = 0; ci < 2; ++ci)
        #pragma unroll
        for (int j = 0; j < 4; ++j)
            *(f32x4*)&mp[(long)(l15 + 16 * j) * CH + c0 + ci * 16 + l4 * 4] = acc[ci][j];
}

// ---------------- mu normalize: sum 16 partials, l2norm, emit 3 formats -----
__global__ __launch_bounds__(256) void mu_norm2(
    const float* __restrict__ macc, const float* __restrict__ zsum,
    float* __restrict__ mu_cur, _Float16* __restrict__ mu16,
    _Float16* __restrict__ muF)
{
    int gw = blockIdx.x * 4 + (threadIdx.x >> 6);   // 512 = 8b x 64k
    int lane = threadIdx.x & 63;
    int b = gw >> 6, k = gw & 63;
    float v[8];
    float s = 0.f;
    #pragma unroll
    for (int ci = 0; ci < 8; ++ci) {
        int c = ci * 64 + lane;
        float a = 0.f;
        #pragma unroll
        for (int pcc = 0; pcc < 16; ++pcc)
            a += macc[(((long)pcc * BB + b) * K + k) * CH + c];
        v[ci] = a; s += a * a;
    }
    #pragma unroll
    for (int off = 1; off < 64; off <<= 1) s += __shfl_xor(s, off, 64);
    float d = 1e-6f + zsum[b * 64 + k];
    float scale = 1.f / (1e-6f * d + sqrtf(s));
    long mb = (long)b << 15;
    #pragma unroll
    for (int ci = 0; ci < 8; ++ci) {
        int c = ci * 64 + lane;
        float m = v[ci] * scale;
        mu_cur[mb + (long)c * K + k] = m;
        mu16[mb + (long)c * K + k] = (_Float16)m;
        muF[mufrag_idx(b, c, k)] = (_Float16)m;
    }
}

// ---------------- rec: recT[p][c] = relu(sum_k z16[p][k]*mu16[c][k]) --------
__global__ __launch_bounds__(256) void rec_mfma(
    const _Float16* __restrict__ z16, const _Float16* __restrict__ mu16,
    _Float16* __restrict__ recT)
{
    __shared__ _Float16 rt[64 * 80];
    int t = threadIdx.x;
    int w = t >> 6, lane = t & 63, l15 = lane & 15, l4 = lane >> 4;
    int p0 = blockIdx.x * 64, ct = blockIdx.y, b = blockIdx.z;
    const _Float16* zb = z16 + (long)b * NP * K;
    const _Float16* mb = mu16 + ((long)b << 15) + (long)(ct * 64 + w * 16 + l15) * K + l4 * 8;
    f32x4 acc[4];
    #pragma unroll
    for (int pj = 0; pj < 4; ++pj) acc[pj] = (f32x4){0.f, 0.f, 0.f, 0.f};
    #pragma unroll
    for (int kc = 0; kc < 64; kc += 32) {
        f16x8 bfr = *(const f16x8*)(mb + kc);
        #pragma unroll
        for (int pj = 0; pj < 4; ++pj) {
            f16x8 a = *(const f16x8*)(zb + (long)(p0 + pj * 16 + l15) * K + kc + l4 * 8);
            acc[pj] = __builtin_amdgcn_mfma_f32_16x16x32_f16(a, bfr, acc[pj], 0, 0, 0);
        }
    }
    #pragma unroll
    for (int pj = 0; pj < 4; ++pj)
        #pragma unroll
        for (int i = 0; i < 4; ++i)
            rt[(pj * 16 + l4 * 4 + i) * 80 + w * 16 + l15] = (_Float16)fmaxf(acc[pj][i], 0.f);
    __syncthreads();
    #pragma unroll
    for (int it = 0; it < 2; ++it) {
        int l = t + it * 256;
        int row = l >> 3, s8 = l & 7;
        *(s16x8*)&recT[((long)b * NP + p0 + row) * CH + ct * 64 + s8 * 8] =
            *(const s16x8*)&rt[row * 80 + s8 * 8];
    }
}

// ---------------- BN stats: 1 block/channel, coalesced f16x4, no atomics ----
__global__ __launch_bounds__(256) void bn_stats2(const _Float16* __restrict__ y2h,
                                                 float* __restrict__ stats,
                                                 float* __restrict__ statsq)
{
    int d = blockIdx.x;
    int t = threadIdx.x;
    float s = 0.f, q = 0.f;
    for (int bi = 0; bi < BI; ++bi) {
        const _Float16* p = y2h + (long)bi * CH * HW + (long)d * HW;
        f16x4 v = *(const f16x4*)&p[t * 4];
        float v0 = (float)v[0], v1 = (float)v[1], v2 = (float)v[2], v3 = (float)v[3];
        s += v0 + v1 + v2 + v3;
        q += v0 * v0 + v1 * v1 + v2 * v2 + v3 * v3;
    }
    #pragma unroll
    for (int off = 1; off < 64; off <<= 1) {
        s += __shfl_xor(s, off, 64);
        q += __shfl_xor(q, off, 64);
    }
    __shared__ float ps[8];
    int wv = t >> 6, ln = t & 63;
    if (ln == 0) { ps[wv] = s; ps[4 + wv] = q; }
    __syncthreads();
    if (t == 0) {
        stats[d]  = ps[0] + ps[1] + ps[2] + ps[3];
        statsq[d] = ps[4] + ps[5] + ps[6] + ps[7];
    }
}

// ---------------- finale: BN + residual + relu, plus mu_b copy --------------
__global__ __launch_bounds__(256) void final_kernel(
    const _Float16* __restrict__ y2h, const float* __restrict__ x,
    const float* __restrict__ stats, const float* __restrict__ statsq,
    const float* __restrict__ gamma, const float* __restrict__ beta,
    const float* __restrict__ mu_cur, float* __restrict__ out)
{
    long i4 = (long)blockIdx.x * 256 + threadIdx.x;
    const long NMAIN4 = (long)BI * CH * HW / 4;     // 5242880
    if (i4 < NMAIN4) {
        long i = i4 * 4;
        int d = (int)((i >> 10) & (CH - 1));
        float s = stats[d], sq = statsq[d];
        const float inv = 1.f / (float)(BI * HW);
        float mean = s * inv;
        float var = sq * inv - mean * mean;
        float rs = rsqrtf(var + 1e-5f);
        float g = rs * gamma[d];
        float bb = beta[d] - mean * g;
        f16x4 yv = *(const f16x4*)&y2h[i];
        float4 xv = *(const float4*)&x[i];
        float4 ov;
        ov.x = fmaxf((float)yv[0] * g + bb + xv.x, 0.f);
        ov.y = fmaxf((float)yv[1] * g + bb + xv.y, 0.f);
        ov.z = fmaxf((float)yv[2] * g + bb + xv.z, 0.f);
        ov.w = fmaxf((float)yv[3] * g + bb + xv.w, 0.f);
        *(float4*)&out[i] = ov;
    } else {
        long j = (i4 - NMAIN4) * 4;                 // mu tail: 262144 elements
        *(float4*)&out[(long)BI * CH * HW + j] = *(const float4*)&mu_cur[j];
    }
}

extern "C" void kernel_launch(void* const* d_in, const int* in_sizes, int n_in,
                              void* d_out, int out_size, void* d_ws, size_t ws_size,
                              hipStream_t stream) {
    const float* x   = (const float*)d_in[0];
    const float* mu0 = (const float*)d_in[1];
    const float* w1  = (const float*)d_in[2];
    const float* b1  = (const float*)d_in[3];
    const float* w2  = (const float*)d_in[4];
    const float* gm  = (const float*)d_in[5];
    const float* bt  = (const float*)d_in[6];
    float* out = (float*)d_out;

    float* ws = (float*)d_ws;
    // Round-10 proven layout (all reuse overlaps sequence-verified):
    _Float16* y16h  = (_Float16*)(ws);              // [8][512][5120]
    _Float16* yT16h = (_Float16*)(ws + 10485760);   // [8][5120][512] (reused as recT)
    _Float16* xTh   = (_Float16*)(ws + 20971520);   // [40960][512]
    _Float16* zTh   = (_Float16*)(ws + 20971520);   // [8][64][5120] (reuses xT)
    _Float16* z16h  = (_Float16*)(ws + 22282240);   // [8][5120][64]
    _Float16* y2h   = (_Float16*)(ws + 20971520);   // [40][512][1024] (reuses zT/z16/macc)
    float*    macc  = ws + 23592960;                // [16][8][64][512]
    float*    mu_cur = ws + 31457280;               // 262,144 f
    _Float16* Wh1   = (_Float16*)(ws + 31719424);
    _Float16* Wh2   = (_Float16*)(ws + 31850496);
    _Float16* mu16h = (_Float16*)(ws + 31981568);
    _Float16* muFh  = (_Float16*)(ws + 32112640);
    float*    zsum  = ws + 32243712;                // [5][512] + stats + statsq contiguous
    float*    stats = ws + 32246272;
    float*    statsq = ws + 32246784;

    // fused setup: Wh1/Wh2/mu_cur/muF + zero zsum/stats/statsq (1 dispatch)
    setup_kernel<<<(262144 + 3584 + 255) / 256, 256, 0, stream>>>(
        w1, w2, mu0, Wh1, Wh2, mu_cur, muFh, zsum);

    transpose_f16<<<dim3(16, 8, 40), 256, 0, stream>>>(x, xTh, HW);
    conv_tile<<<1280, 256, 0, stream>>>(Wh1, xTh, b1, nullptr, y16h, yT16h, 0);

    for (int s = 0; s < 5; ++s) {
        stage_z_mfma<<<dim3(80, 8), 256, 0, stream>>>(yT16h, muFh, zTh, z16h,
                                                      zsum + s * 512, s == 4);
        stage_mu_mfma<<<dim3(16, 4, 8), 256, 0, stream>>>(y16h, zTh, macc);
        mu_norm2<<<128, 256, 0, stream>>>(macc, zsum + s * 512, mu_cur, mu16h, muFh);
    }

    // rec overwrites yT16 region (dead after last stage_z)
    rec_mfma<<<dim3(80, 8, 8), 256, 0, stream>>>(z16h, mu16h, yT16h);
    // conv2 writes fp16 y2 into the (now dead) zT/z16/macc region
    conv_tile<<<1280, 256, 0, stream>>>(Wh2, yT16h, nullptr, y2h, nullptr, nullptr, 1);
    bn_stats2<<<512, 256, 0, stream>>>(y2h, stats, statsq);
    long total4 = ((long)BI * CH * HW + (long)BB * CH * K) / 4;
    final_kernel<<<(int)((total4 + 255) / 256), 256, 0, stream>>>(
        y2h, x, stats, statsq, gm, bt, mu_cur, out);
}